// Round 3
// baseline (169.453 us; speedup 1.0000x reference)
//
#include <hip/hip_runtime.h>
#include <hip/hip_bf16.h>
#include <math.h>

#define EMBED 768
#define NTOK  4096
#define NB    4
#define ROWS  16384          // 4 * 4096
#define CN    192            // Q(64)|K(64)|V(64)

typedef __attribute__((ext_vector_type(8))) short bf16x8;       // 8 bf16 = 4 VGPR
typedef __attribute__((ext_vector_type(4))) float f32x4;        // MFMA acc
typedef __attribute__((ext_vector_type(4))) unsigned int u32x4; // 4 dwords

// Split fp32 -> h + l bf16 via packed RNE converts (~3 VALU/elem).
// f = h + l + eps, |eps| ~ 2^-18 |f|  (d = f - h is exact in fp32).
__device__ inline void split8(const float4& a0, const float4& a1,
                              bf16x8& h, bf16x8& l) {
  const float f[8] = {a0.x, a0.y, a0.z, a0.w, a1.x, a1.y, a1.z, a1.w};
  u32x4 hw, lw;
#pragma unroll
  for (int j = 0; j < 4; ++j) {
    float2 p = make_float2(f[2 * j], f[2 * j + 1]);
    __hip_bfloat162 hb = __float22bfloat162_rn(p);
    float2 hf = __bfloat1622float2(hb);
    __hip_bfloat162 lb =
        __float22bfloat162_rn(make_float2(p.x - hf.x, p.y - hf.y));
    union { __hip_bfloat162 b; unsigned u; } cu, cl;
    cu.b = hb; cl.b = lb;
    hw[j] = cu.u; lw[j] = cl.u;
  }
  h = __builtin_bit_cast(bf16x8, hw);
  l = __builtin_bit_cast(bf16x8, lw);
}

__device__ inline void split1(float f, unsigned short& h, unsigned short& l) {
  __hip_bfloat16 hb = __float2bfloat16(f);
  float hf = __bfloat162float(hb);
  __hip_bfloat16 lb = __float2bfloat16(f - hf);
  union { __hip_bfloat16 b; unsigned short u; } a, b2;
  a.b = hb; b2.b = lb;
  h = a.u; l = b2.u;
}

// ---------------------------------------------------------------------------
// W prep: Wt[plane][n][k] bf16 (plane 0 = high, 1 = low), n in [0,192).
// t = k*192 + c  ->  reads coalesced within each source matrix.
// ---------------------------------------------------------------------------
__global__ __launch_bounds__(256) void wprep(const float* __restrict__ Wq,
                                             const float* __restrict__ Wk,
                                             const float* __restrict__ Wv,
                                             unsigned short* __restrict__ Wt) {
  int t = blockIdx.x * 256 + threadIdx.x;   // 768*192 threads
  int k = t / CN, c = t - k * CN;
  float w;
  if (c < 64)        w = Wq[k * 64 + c];
  else if (c < 128)  w = Wk[k * 64 + (c - 64)];
  else               w = Wv[k * 64 + (c - 128)];
  unsigned short h, l; split1(w, h, l);
  Wt[(size_t)c * EMBED + k]          = h;
  Wt[(size_t)(CN + c) * EMBED + k]   = l;
}

// ---------------------------------------------------------------------------
// MFMA GEMM: C[16384][192] = x @ W + bias, split-bf16 (3 MFMA passes).
// Block: 384 thr = 6 waves, one m=32 row-panel, wave wn covers n [wn*32,+32).
// Wave tile 32x32 = 2x2 tiles of 16x16x32. Grid 512 blocks -> 3072 waves
// (3 waves/SIMD). A loads are L1-hot (shared across the 6 waves); B from L2.
// ---------------------------------------------------------------------------
__global__ __launch_bounds__(384, 3) void qkv_mfma(
    const float* __restrict__ x, const unsigned short* __restrict__ Wtu,
    const float* __restrict__ bq, const float* __restrict__ bk,
    const float* __restrict__ bv, float* __restrict__ C) {
  const int lane = threadIdx.x & 63;
  const int wn   = threadIdx.x >> 6;   // 0..5 : n-group
  const int ml   = lane & 15;
  const int qd   = lane >> 4;          // quad: k = qd*8 + j
  const int r0   = blockIdx.x * 32;
  const int n0   = wn * 32;

  f32x4 acc[2][2] = {};                // [mt][nt]

  const float* xa0 = x + (size_t)(r0 + ml) * EMBED + qd * 8;
  const float* xa1 = x + (size_t)(r0 + 16 + ml) * EMBED + qd * 8;
  const bf16x8* wt = (const bf16x8*)Wtu;

  // B frag index in bf16x8 units: (pl*192 + n)*96 + ks*4 + qd
  int bidx[2][2];
#pragma unroll
  for (int pl = 0; pl < 2; ++pl)
#pragma unroll
    for (int nt = 0; nt < 2; ++nt)
      bidx[pl][nt] = (pl * CN + n0 + nt * 16 + ml) * 96 + qd;

  float4 ca[2][2];                     // [mt][half]
  bf16x8 cb[2][2];                     // [pl][nt]
  ca[0][0] = *(const float4*)(xa0);  ca[0][1] = *(const float4*)(xa0 + 4);
  ca[1][0] = *(const float4*)(xa1);  ca[1][1] = *(const float4*)(xa1 + 4);
#pragma unroll
  for (int pl = 0; pl < 2; ++pl)
#pragma unroll
    for (int nt = 0; nt < 2; ++nt) cb[pl][nt] = wt[bidx[pl][nt]];

  for (int ks = 0; ks < 24; ++ks) {
    float4 na[2][2]; bf16x8 nb[2][2];
    if (ks < 23) {
      const float* p0 = xa0 + (ks + 1) * 32;
      const float* p1 = xa1 + (ks + 1) * 32;
      na[0][0] = *(const float4*)(p0);  na[0][1] = *(const float4*)(p0 + 4);
      na[1][0] = *(const float4*)(p1);  na[1][1] = *(const float4*)(p1 + 4);
      const int ko = (ks + 1) * 4;
#pragma unroll
      for (int pl = 0; pl < 2; ++pl)
#pragma unroll
        for (int nt = 0; nt < 2; ++nt) nb[pl][nt] = wt[bidx[pl][nt] + ko];
    }

    bf16x8 ah[2], al[2];
    split8(ca[0][0], ca[0][1], ah[0], al[0]);
    split8(ca[1][0], ca[1][1], ah[1], al[1]);

#pragma unroll
    for (int mt = 0; mt < 2; ++mt)
#pragma unroll
      for (int nt = 0; nt < 2; ++nt) {
        acc[mt][nt] = __builtin_amdgcn_mfma_f32_16x16x32_bf16(
            al[mt], cb[0][nt], acc[mt][nt], 0, 0, 0);
        acc[mt][nt] = __builtin_amdgcn_mfma_f32_16x16x32_bf16(
            ah[mt], cb[1][nt], acc[mt][nt], 0, 0, 0);
        acc[mt][nt] = __builtin_amdgcn_mfma_f32_16x16x32_bf16(
            ah[mt], cb[0][nt], acc[mt][nt], 0, 0, 0);
      }

#pragma unroll
    for (int mt = 0; mt < 2; ++mt) {
      ca[mt][0] = na[mt][0]; ca[mt][1] = na[mt][1];
    }
#pragma unroll
    for (int pl = 0; pl < 2; ++pl)
#pragma unroll
      for (int nt = 0; nt < 2; ++nt) cb[pl][nt] = nb[pl][nt];
  }

  // epilogue: bias + store. C/D: col = lane&15 (n), row = qd*4 + reg (m).
#pragma unroll
  for (int nt = 0; nt < 2; ++nt) {
    int n = n0 + nt * 16 + ml;
    float bias = (n < 64) ? bq[n] : (n < 128) ? bk[n - 64] : bv[n - 128];
#pragma unroll
    for (int mt = 0; mt < 2; ++mt)
#pragma unroll
      for (int reg = 0; reg < 4; ++reg) {
        int row = r0 + mt * 16 + qd * 4 + reg;
        C[(size_t)row * CN + n] = acc[mt][nt][reg] + bias;
      }
  }
}

// ---------------------------------------------------------------------------
// Vsum[b][d] = sum_r V[b,r,d]
// ---------------------------------------------------------------------------
__global__ __launch_bounds__(256) void vsum_kernel(const float* __restrict__ C,
                                                   float* __restrict__ Vsum) {
  __shared__ float red[4][64];
  const int t = threadIdx.x;
  const int d = t & 63;
  const int g = t >> 6;
  const int batch = blockIdx.x >> 6;
  const int chunk = blockIdx.x & 63;
  const size_t base =
      ((size_t)batch * NTOK + (size_t)chunk * 64 + (size_t)g * 16) * CN + 128 + d;
  float s = 0.f;
#pragma unroll
  for (int rr = 0; rr < 16; ++rr) s += C[base + (size_t)rr * CN];
  red[g][d] = s;
  __syncthreads();
  if (g == 0) {
    atomicAdd(&Vsum[batch * 64 + d],
              red[0][d] + red[1][d] + red[2][d] + red[3][d]);
  }
}

// ---------------------------------------------------------------------------
// Per-row scores + softmax-with-zero-background + V combine (faithful quirk).
// ---------------------------------------------------------------------------
__global__ __launch_bounds__(256) void attn_kernel(const float* __restrict__ C,
                                                   const float* __restrict__ Vsum,
                                                   float* __restrict__ out) {
  const int t    = threadIdx.x;
  const int lane = t & 63;
  const int wave = t >> 6;
  const int r = blockIdx.x * 4 + wave;
  const int b = r >> 12;
  const int i = r & (NTOK - 1);

  const float q  = C[(size_t)r * CN + lane];
  const float kc = C[(size_t)r * CN + 64 + lane];
  float km = 0.f, kp = 0.f;
  if (i > 0)        km = C[(size_t)(r - 1) * CN + 64 + lane];
  if (i < NTOK - 1) kp = C[(size_t)(r + 1) * CN + 64 + lane];

  float p0 = q * km, p1 = q * kc, p2 = q * kp;
#pragma unroll
  for (int off = 32; off > 0; off >>= 1) {
    p0 += __shfl_xor(p0, off, 64);
    p1 += __shfl_xor(p1, off, 64);
    p2 += __shfl_xor(p2, off, 64);
  }

  const float s0 = (i > 0) ? p0 : 0.f;
  const float s1 = p1;
  const float s2 = (i < NTOK - 1) ? p2 : 0.f;
  const float m  = fmaxf(fmaxf(s0, s1), fmaxf(s2, 0.f));
  const float e0 = expf(s0 - m);
  const float e1 = expf(s1 - m);
  const float e2 = expf(s2 - m);
  const float ez = expf(-m);
  const float Z  = e0 + e1 + e2 + (float)(NTOK - 3) * ez;

  const size_t vb = ((size_t)b * NTOK) * CN + 128;
  const float v0 = C[vb + lane];
  const float v1 = C[vb + CN + lane];
  const float v2 = C[vb + 2 * (size_t)CN + lane];
  const float vs = Vsum[b * 64 + lane];

  out[(size_t)r * 64 + lane] =
      (e0 * v0 + e1 * v1 + e2 * v2 + ez * (vs - v0 - v1 - v2)) / Z;
}

// ---------------------------------------------------------------------------
extern "C" void kernel_launch(void* const* d_in, const int* in_sizes, int n_in,
                              void* d_out, int out_size, void* d_ws, size_t ws_size,
                              hipStream_t stream) {
  const float* x  = (const float*)d_in[0];
  const float* Wq = (const float*)d_in[1];
  const float* bq = (const float*)d_in[2];
  const float* Wk = (const float*)d_in[3];
  const float* bk = (const float*)d_in[4];
  const float* Wv = (const float*)d_in[5];
  const float* bv = (const float*)d_in[6];
  float* out = (float*)d_out;

  float* C    = (float*)d_ws;                       // 16384 x 192 fp32 (12 MiB)
  float* Vsum = C + (size_t)ROWS * CN;              // 4 x 64
  unsigned short* Wt = (unsigned short*)(Vsum + NB * 64);  // 2 x 192 x 768 bf16

  hipMemsetAsync(Vsum, 0, NB * 64 * sizeof(float), stream);
  wprep<<<576, 256, 0, stream>>>(Wq, Wk, Wv, Wt);
  qkv_mfma<<<512, 384, 0, stream>>>(x, Wt, bq, bk, bv, C);
  vsum_kernel<<<256, 256, 0, stream>>>(C, Vsum);
  attn_kernel<<<ROWS / 4, 256, 0, stream>>>(C, Vsum, out);
}

// Round 4
// 161.578 us; speedup vs baseline: 1.0487x; 1.0487x over previous
//
#include <hip/hip_runtime.h>
#include <hip/hip_bf16.h>
#include <math.h>

#define EMBED 768
#define NTOK  4096
#define NB    4
#define ROWS  16384          // 4 * 4096
#define CN    192            // Q(64)|K(64)|V(64)

typedef __attribute__((ext_vector_type(8))) short bf16x8;       // 8 bf16 = 4 VGPR
typedef __attribute__((ext_vector_type(4))) float f32x4;        // MFMA acc
typedef __attribute__((ext_vector_type(4))) unsigned int u32x4; // 4 dwords

// Split fp32 -> h + l bf16 via packed RNE converts (~3 VALU/elem).
// f = h + l + eps, |eps| ~ 2^-18 |f|  (f - h is exact in fp32).
__device__ inline void split8(const float4& a0, const float4& a1,
                              bf16x8& h, bf16x8& l) {
  const float f[8] = {a0.x, a0.y, a0.z, a0.w, a1.x, a1.y, a1.z, a1.w};
  u32x4 hw, lw;
#pragma unroll
  for (int j = 0; j < 4; ++j) {
    float2 p = make_float2(f[2 * j], f[2 * j + 1]);
    __hip_bfloat162 hb = __float22bfloat162_rn(p);
    float2 hf = __bfloat1622float2(hb);
    __hip_bfloat162 lb =
        __float22bfloat162_rn(make_float2(p.x - hf.x, p.y - hf.y));
    union { __hip_bfloat162 b; unsigned u; } cu, cl;
    cu.b = hb; cl.b = lb;
    hw[j] = cu.u; lw[j] = cl.u;
  }
  h = __builtin_bit_cast(bf16x8, hw);
  l = __builtin_bit_cast(bf16x8, lw);
}

__device__ inline void split1(float f, unsigned short& h, unsigned short& l) {
  __hip_bfloat16 hb = __float2bfloat16(f);
  float hf = __bfloat162float(hb);
  __hip_bfloat16 lb = __float2bfloat16(f - hf);
  union { __hip_bfloat16 b; unsigned short u; } a, b2;
  a.b = hb; b2.b = lb;
  h = a.u; l = b2.u;
}

// ---------------------------------------------------------------------------
// W prep: Wt[plane][n][k] bf16 (plane 0 = high, 1 = low), n in [0,192).
// ---------------------------------------------------------------------------
__global__ __launch_bounds__(256) void wprep(const float* __restrict__ Wq,
                                             const float* __restrict__ Wk,
                                             const float* __restrict__ Wv,
                                             unsigned short* __restrict__ Wt) {
  int t = blockIdx.x * 256 + threadIdx.x;   // 768*192 threads
  int k = t / CN, c = t - k * CN;
  float w;
  if (c < 64)        w = Wq[k * 64 + c];
  else if (c < 128)  w = Wk[k * 64 + (c - 64)];
  else               w = Wv[k * 64 + (c - 128)];
  unsigned short h, l; split1(w, h, l);
  Wt[(size_t)c * EMBED + k]        = h;
  Wt[(size_t)(CN + c) * EMBED + k] = l;
}

// ---------------------------------------------------------------------------
// MFMA GEMM: C[16384][192] = x @ W + bias, split-bf16.
// Q/K columns (n<128): 3 MFMA passes (ah*bh + al*bh + ah*bl).
// V columns (n>=128): 1 pass (bf16 error on V is below the output floor).
// Block: 512 thr = 8 waves. Tile M=32 (2 m-waves x 16 rows), N=192
// (4 n-groups x 48). x staged fp32 into double-buffered LDS (stride 68).
// Grid 512 blocks -> 4096 waves = 4 waves/SIMD. B frags direct from L2.
// Epilogue also reduces V tiles over rows -> atomicAdd into Vsum (fused vsum).
// ---------------------------------------------------------------------------
__global__ __launch_bounds__(512) void qkv_mfma(
    const float* __restrict__ x, const unsigned short* __restrict__ Wtu,
    const float* __restrict__ bq, const float* __restrict__ bk,
    const float* __restrict__ bv, float* __restrict__ C,
    float* __restrict__ Vsum) {
  __shared__ float xs[2][32][68];

  const int t    = threadIdx.x;
  const int lane = t & 63;
  const int w    = t >> 6;          // 0..7
  const int wn   = w & 3;           // n-group: cols [wn*48, wn*48+48)
  const int mt   = w >> 2;          // m-half: rows [mt*16, mt*16+16)
  const int ml   = lane & 15;
  const int qd   = lane >> 4;       // quad: k = qd*8 + j
  const int r0   = blockIdx.x * 32;
  const int nb0  = wn * 48;
  const int batch = blockIdx.x >> 7;   // 128 blocks per batch

  const bf16x8* wt = (const bf16x8*)Wtu;

  // B frag bases in bf16x8 units: (plane*192 + n)*96 + qd  (+ s*8 + c*4)
  int bh_base[3], bl_base[3];
#pragma unroll
  for (int j = 0; j < 3; ++j) {
    int n = nb0 + j * 16 + ml;
    bh_base[j] = n * 96 + qd;
    bl_base[j] = (CN + n) * 96 + qd;
  }

  f32x4 acc[3] = {};

  // staging: thread t loads float4 of x[r0 + (t>>4)][(t&15)*4 + s*64]
  const int srow = t >> 4;          // 0..31
  const int skq  = (t & 15) * 4;
  const float* xg = x + (size_t)(r0 + srow) * EMBED + skq;

  float4 sreg = *(const float4*)(xg);
  *(float4*)&xs[0][srow][skq] = sreg;
  __syncthreads();

  for (int s = 0; s < 12; ++s) {
    const int cur = s & 1;
    float4 nreg;
    if (s < 11) nreg = *(const float4*)(xg + (s + 1) * 64);

    // A fragments from LDS (two k-chunks of 32)
    bf16x8 ah[2], al[2];
#pragma unroll
    for (int c = 0; c < 2; ++c) {
      float4 f0 = *(const float4*)&xs[cur][mt * 16 + ml][c * 32 + qd * 8];
      float4 f1 = *(const float4*)&xs[cur][mt * 16 + ml][c * 32 + qd * 8 + 4];
      split8(f0, f1, ah[c], al[c]);
    }

#pragma unroll
    for (int j = 0; j < 3; ++j) {
      const bool full = (nb0 + j * 16) < 128;   // wave-uniform
#pragma unroll
      for (int c = 0; c < 2; ++c) {
        bf16x8 bh = wt[bh_base[j] + s * 8 + c * 4];
        acc[j] = __builtin_amdgcn_mfma_f32_16x16x32_bf16(ah[c], bh, acc[j], 0, 0, 0);
        if (full) {
          bf16x8 bl = wt[bl_base[j] + s * 8 + c * 4];
          acc[j] = __builtin_amdgcn_mfma_f32_16x16x32_bf16(al[c], bh, acc[j], 0, 0, 0);
          acc[j] = __builtin_amdgcn_mfma_f32_16x16x32_bf16(ah[c], bl, acc[j], 0, 0, 0);
        }
      }
    }

    if (s < 11) *(float4*)&xs[cur ^ 1][srow][skq] = nreg;
    __syncthreads();
  }

  // epilogue: bias, fused Vsum reduction, store.
  // C/D layout: col = lane&15 (n), row = qd*4 + reg (m).
#pragma unroll
  for (int j = 0; j < 3; ++j) {
    const int n = nb0 + j * 16 + ml;
    const float bias = (n < 64) ? bq[n] : (n < 128) ? bk[n - 64] : bv[n - 128];
    float o[4];
#pragma unroll
    for (int reg = 0; reg < 4; ++reg) o[reg] = acc[j][reg] + bias;

    if (nb0 + j * 16 >= 128) {              // V tile: reduce rows -> Vsum
      float ssum = o[0] + o[1] + o[2] + o[3];
      ssum += __shfl_xor(ssum, 16, 64);
      ssum += __shfl_xor(ssum, 32, 64);
      if (qd == 0) atomicAdd(&Vsum[batch * 64 + (n - 128)], ssum);
    }
#pragma unroll
    for (int reg = 0; reg < 4; ++reg) {
      int row = r0 + mt * 16 + qd * 4 + reg;
      C[(size_t)row * CN + n] = o[reg];
    }
  }
}

// ---------------------------------------------------------------------------
// Per-row scores + softmax-with-zero-background + V combine (faithful quirk).
// ---------------------------------------------------------------------------
__global__ __launch_bounds__(256) void attn_kernel(const float* __restrict__ C,
                                                   const float* __restrict__ Vsum,
                                                   float* __restrict__ out) {
  const int t    = threadIdx.x;
  const int lane = t & 63;
  const int wave = t >> 6;
  const int r = blockIdx.x * 4 + wave;
  const int b = r >> 12;
  const int i = r & (NTOK - 1);

  const float q  = C[(size_t)r * CN + lane];
  const float kc = C[(size_t)r * CN + 64 + lane];
  float km = 0.f, kp = 0.f;
  if (i > 0)        km = C[(size_t)(r - 1) * CN + 64 + lane];
  if (i < NTOK - 1) kp = C[(size_t)(r + 1) * CN + 64 + lane];

  float p0 = q * km, p1 = q * kc, p2 = q * kp;
#pragma unroll
  for (int off = 32; off > 0; off >>= 1) {
    p0 += __shfl_xor(p0, off, 64);
    p1 += __shfl_xor(p1, off, 64);
    p2 += __shfl_xor(p2, off, 64);
  }

  const float s0 = (i > 0) ? p0 : 0.f;
  const float s1 = p1;
  const float s2 = (i < NTOK - 1) ? p2 : 0.f;
  const float m  = fmaxf(fmaxf(s0, s1), fmaxf(s2, 0.f));
  const float e0 = expf(s0 - m);
  const float e1 = expf(s1 - m);
  const float e2 = expf(s2 - m);
  const float ez = expf(-m);
  const float Z  = e0 + e1 + e2 + (float)(NTOK - 3) * ez;

  const size_t vb = ((size_t)b * NTOK) * CN + 128;
  const float v0 = C[vb + lane];
  const float v1 = C[vb + CN + lane];
  const float v2 = C[vb + 2 * (size_t)CN + lane];
  const float vs = Vsum[b * 64 + lane];

  out[(size_t)r * 64 + lane] =
      (e0 * v0 + e1 * v1 + e2 * v2 + ez * (vs - v0 - v1 - v2)) / Z;
}

// ---------------------------------------------------------------------------
extern "C" void kernel_launch(void* const* d_in, const int* in_sizes, int n_in,
                              void* d_out, int out_size, void* d_ws, size_t ws_size,
                              hipStream_t stream) {
  const float* x  = (const float*)d_in[0];
  const float* Wq = (const float*)d_in[1];
  const float* bq = (const float*)d_in[2];
  const float* Wk = (const float*)d_in[3];
  const float* bk = (const float*)d_in[4];
  const float* Wv = (const float*)d_in[5];
  const float* bv = (const float*)d_in[6];
  float* out = (float*)d_out;

  float* C    = (float*)d_ws;                       // 16384 x 192 fp32 (12 MiB)
  float* Vsum = C + (size_t)ROWS * CN;              // 4 x 64
  unsigned short* Wt = (unsigned short*)(Vsum + NB * 64);  // 2 x 192 x 768 bf16

  hipMemsetAsync(Vsum, 0, NB * 64 * sizeof(float), stream);
  wprep<<<576, 256, 0, stream>>>(Wq, Wk, Wv, Wt);
  qkv_mfma<<<512, 512, 0, stream>>>(x, Wt, bq, bk, bv, C, Vsum);
  attn_kernel<<<ROWS / 4, 256, 0, stream>>>(C, Vsum, out);
}